// Round 26
// baseline (725.669 us; speedup 1.0000x reference)
//
#include <hip/hip_runtime.h>
#include <hip/hip_bf16.h>

typedef __attribute__((ext_vector_type(8))) short short8;
typedef __attribute__((ext_vector_type(4))) float floatx4;
typedef unsigned short ushort_t;

__device__ inline float b2f(ushort_t s) {
    return __uint_as_float(((unsigned int)s) << 16);
}
__device__ inline ushort_t f2b(float f) {
    unsigned int u = __float_as_uint(f);
    unsigned int r = 0x7fff + ((u >> 16) & 1);
    return (ushort_t)((u + r) >> 16);
}
__device__ inline unsigned int cvtpk(float lo, float hi) {
    unsigned int r;
    asm("v_cvt_pk_bf16_f32 %0, %1, %2" : "=v"(r) : "v"(lo), "v"(hi));
    return r;
}
__device__ inline void load8(const float* p, float* f) {
    float4 a = *(const float4*)p;
    float4 b = *(const float4*)(p + 4);
    f[0] = a.x; f[1] = a.y; f[2] = a.z; f[3] = a.w;
    f[4] = b.x; f[5] = b.y; f[6] = b.z; f[7] = b.w;
}
__device__ inline void gload16(const ushort_t* g, ushort_t* l) {
    __builtin_amdgcn_global_load_lds(
        (const __attribute__((address_space(1))) unsigned int*)g,
        (__attribute__((address_space(3))) unsigned int*)l, 16, 0, 0);
}
__device__ inline void lbar() {
    asm volatile("s_waitcnt lgkmcnt(0)" ::: "memory");
    __builtin_amdgcn_s_barrier();
    asm volatile("" ::: "memory");
}
__device__ inline void drainbar() {
    asm volatile("s_waitcnt vmcnt(0) lgkmcnt(0)" ::: "memory");
    __builtin_amdgcn_s_barrier();
    asm volatile("" ::: "memory");
}

// ---------- merged pre-pass: weight fp32 [K,N] -> bf16 [N,K]  +  rmsnorm1 (ids >= 15872) ----------
__global__ __launch_bounds__(256) void transpose_all(
    const float* __restrict__ s0, const float* __restrict__ s1,
    const float* __restrict__ s2, const float* __restrict__ s3,
    const float* __restrict__ s4, const float* __restrict__ s5,
    const float* __restrict__ s6, const float* __restrict__ s7,
    ushort_t* d0, ushort_t* d1, ushort_t* d2, ushort_t* d3,
    ushort_t* d4, ushort_t* d5, ushort_t* d6, ushort_t* d7,
    const float* __restrict__ xin, const float* __restrict__ n1w,
    ushort_t* __restrict__ xnout) {
    int id = blockIdx.x;
    int t = threadIdx.x;
    if (id >= 15872) {
        // fused rmsnorm1: one block per row, D=2048
        int row = id - 15872;
        const float* xr = xin + (size_t)row * 2048;
        float f[8];
        load8(xr + t * 8, f);
        float ss = 0.f;
#pragma unroll
        for (int i = 0; i < 8; ++i) ss += f[i] * f[i];
#pragma unroll
        for (int m = 1; m < 64; m <<= 1) ss += __shfl_xor(ss, m);
        __shared__ float wsum[4];
        if ((t & 63) == 0) wsum[t >> 6] = ss;
        __syncthreads();
        float tot = wsum[0] + wsum[1] + wsum[2] + wsum[3];
        float r = rsqrtf(tot / 2048.f + 1e-6f);
        float wf[8];
        load8(n1w + t * 8, wf);
        ushort_t o[8];
#pragma unroll
        for (int i = 0; i < 8; ++i) o[i] = f2b(f[i] * r * wf[i]);
        *(uint4*)(xnout + (size_t)row * 2048 + t * 8) = *(const uint4*)o;
        return;
    }
    const float* src; ushort_t* dst; int K, N;
    if (id < 1024)       { src = s0; dst = d0; K = 2048; N = 2048; }
    else if (id < 1280)  { id -= 1024;  src = s1; dst = d1; K = 2048; N = 512; }
    else if (id < 1536)  { id -= 1280;  src = s2; dst = d2; K = 2048; N = 512; }
    else if (id < 2560)  { id -= 1536;  src = s3; dst = d3; K = 2048; N = 2048; }
    else if (id < 3584)  { id -= 2560;  src = s4; dst = d4; K = 2048; N = 2048; }
    else if (id < 7680)  { id -= 3584;  src = s5; dst = d5; K = 2048; N = 8192; }
    else if (id < 11776) { id -= 7680;  src = s6; dst = d6; K = 2048; N = 8192; }
    else                 { id -= 11776; src = s7; dst = d7; K = 8192; N = 2048; }
    int tn = N >> 6;
    int kb = (id / tn) * 64, nb = (id % tn) * 64;
    __shared__ ushort_t tile[64][65];
#pragma unroll
    for (int i = 0; i < 4; ++i) {
        int r = (t >> 4) + i * 16;
        int c = (t & 15) * 4;
        float4 v = *(const float4*)(src + (size_t)(kb + r) * N + nb + c);
        tile[c + 0][r] = f2b(v.x);
        tile[c + 1][r] = f2b(v.y);
        tile[c + 2][r] = f2b(v.z);
        tile[c + 3][r] = f2b(v.w);
    }
    __syncthreads();
#pragma unroll
    for (int i = 0; i < 2; ++i) {
        int s = t + i * 256;
        int n = s >> 3, kc = (s & 7) * 8;
        ushort_t o[8];
#pragma unroll
        for (int j = 0; j < 8; ++j) o[j] = tile[n][kc + j];
        *(uint4*)(dst + (size_t)(nb + n) * K + kb + kc) = *(const uint4*)o;
    }
}

// ---------------- RMSNorm: fp32 in -> bf16 out ----------------
__global__ __launch_bounds__(256) void rmsnorm_kernel(const float* __restrict__ x,
                                                      const float* __restrict__ w,
                                                      ushort_t* __restrict__ out, int D) {
    int row = blockIdx.x;
    int t = threadIdx.x;
    const float* xr = x + (size_t)row * D;
    float f[8];
    load8(xr + t * 8, f);
    float ss = 0.f;
#pragma unroll
    for (int i = 0; i < 8; ++i) ss += f[i] * f[i];
#pragma unroll
    for (int m = 1; m < 64; m <<= 1) ss += __shfl_xor(ss, m);
    __shared__ float wsum[4];
    if ((t & 63) == 0) wsum[t >> 6] = ss;
    __syncthreads();
    float tot = wsum[0] + wsum[1] + wsum[2] + wsum[3];
    float r = rsqrtf(tot / (float)D + 1e-6f);
    float wf[8];
    load8(w + t * 8, wf);
    ushort_t o[8];
#pragma unroll
    for (int i = 0; i < 8; ++i) o[i] = f2b(f[i] * r * wf[i]);
    *(uint4*)(out + (size_t)row * D + t * 8) = *(const uint4*)o;
}

// ---------------- final reduce: out = p0 + p1 + resid ----------------
__global__ __launch_bounds__(256) void reduce_out(const ushort_t* __restrict__ p,
                                                  const float* __restrict__ resid,
                                                  float* __restrict__ out, int n) {
    int stride = gridDim.x * 256;
    for (int i = blockIdx.x * 256 + threadIdx.x; i * 8 < n; i += stride) {
        int i8 = i * 8;
        uint4 a = *(const uint4*)(p + i8);
        uint4 b = *(const uint4*)(p + n + i8);
        const ushort_t* ae = (const ushort_t*)&a;
        const ushort_t* be = (const ushort_t*)&b;
        float rr[8];
        load8(resid + i8, rr);
        float o[8];
#pragma unroll
        for (int j = 0; j < 8; ++j) o[j] = b2f(ae[j]) + b2f(be[j]) + rr[j];
        *(float4*)(out + i8) = make_float4(o[0], o[1], o[2], o[3]);
        *(float4*)(out + i8 + 4) = make_float4(o[4], o[5], o[6], o[7]);
    }
}

// ---------------- attention split-K merge ----------------
__global__ __launch_bounds__(256) void attn_merge(const ushort_t* __restrict__ Pb,
                                                  const float* __restrict__ Mb,
                                                  const float* __restrict__ Lb,
                                                  ushort_t* __restrict__ out) {
    const int PSZ = 32 * 2048 * 128;
    int t = threadIdx.x;
    int r = blockIdx.x * 16 + (t >> 4);
    int d0 = (t & 15) * 8;
    float m1 = Mb[r], l1 = Lb[r];
    float m2 = Mb[65536 + r], l2 = Lb[65536 + r];
    float ms = fmaxf(m1, m2);
    float w1 = l1 * __expf(m1 - ms);
    float w2 = l2 * __expf(m2 - ms);
    float inv = 1.f / (w1 + w2);
    w1 *= inv; w2 *= inv;
    uint4 a = *(const uint4*)(Pb + (size_t)r * 128 + d0);
    uint4 b = *(const uint4*)(Pb + (size_t)PSZ + (size_t)r * 128 + d0);
    const ushort_t* ae = (const ushort_t*)&a;
    const ushort_t* be = (const ushort_t*)&b;
    int bh = r >> 11, qrow = r & 2047;
    int bb = bh >> 4, h = bh & 15;
    ushort_t o[8];
#pragma unroll
    for (int j = 0; j < 8; ++j) o[j] = f2b(b2f(ae[j]) * w1 + b2f(be[j]) * w2);
    *(uint4*)(out + ((size_t)(bb * 2048 + qrow) * 2048) + h * 128 + d0) = *(const uint4*)o;
}

__device__ inline void vm6() { asm volatile("s_waitcnt vmcnt(6)" ::: "memory"); }
__device__ inline void vm4() { asm volatile("s_waitcnt vmcnt(4)" ::: "memory"); }

// ---------------- 256x256 8-phase GEMM (BK=64, 8 waves, XOR-8 swizzle) ----------------
// MODE 0: C=AB bf16 ; 2: silu(aux)*AB ; 3: K-split partial ; 6: QKV split (staged, per-region)
template <int MODE>
__global__ __launch_bounds__(512, 2) void gemm8(const ushort_t* __restrict__ A,
                                                const ushort_t* __restrict__ Bt,
                                                const ushort_t* __restrict__ aux,
                                                const float* __restrict__ aux2,
                                                void* __restrict__ Cv,
                                                void* __restrict__ C2v,
                                                void* __restrict__ C3v,
                                                int M, int N, int Ksub, int lda) {
    __shared__ __align__(16) ushort_t Lds[2 * 32768];
    const int tid = threadIdx.x;
    const int wv = tid >> 6, lane = tid & 63;
    const int l16 = lane & 15, l4 = lane >> 4;
    const int wr = wv >> 2, wc = wv & 3;
    int nwg = gridDim.x;
    int per = nwg >> 3;
    int wg = (blockIdx.x & 7) * per + (blockIdx.x >> 3);
    int mtiles = M >> 8;
    int bx = wg & (mtiles - 1);
    int by = wg / mtiles;
    int bm = bx << 8, bn = by << 8;
    int koff = blockIdx.y * Ksub;

    const int sr = tid >> 3;
    const int scol = (((tid & 7) ^ (sr & 7)) << 3);
    const ushort_t* gA = A + (size_t)(bm + sr) * lda + scol + koff;
    const ushort_t* gB = Bt + (size_t)(bn + sr) * lda + scol + koff;
    ushort_t* ldsw = Lds + wv * 512;

    const int ktiles = Ksub >> 6;
    const int niter = ktiles >> 1;
    const int km = ktiles - 1;

#define STG_A(slot, j, kt) gload16(gA + (size_t)((j) * 64) * lda + ((kt) << 6), ldsw + (slot) * 32768 + (j) * 4096)
#define STG_B(slot, j, kt) gload16(gB + (size_t)((j) * 64) * lda + ((kt) << 6), ldsw + (slot) * 32768 + 16384 + (j) * 4096)

    STG_A(0, 0, 0); STG_A(0, 2, 0); STG_A(0, 1, 0); STG_A(0, 3, 0);
    STG_B(0, 0, 0); STG_B(0, 1, 0); STG_B(0, 2, 0); STG_B(0, 3, 0);
    STG_A(1, 0, 1); STG_A(1, 2, 1);
    STG_B(1, 0, 1); STG_B(1, 1, 1); STG_B(1, 2, 1); STG_B(1, 3, 1);
    vm6();
    asm volatile("" ::: "memory");
    __builtin_amdgcn_s_barrier();

    const int lx = l4 ^ (l16 & 7);
    floatx4 acc[8][4] = {};
    short8 aR[4][2], bR[4][2];

#define DSA(slot, mh) { _Pragma("unroll") for (int m = 0; m < 4; ++m) { \
    _Pragma("unroll") for (int kk = 0; kk < 2; ++kk) \
      aR[m][kk] = *(const short8*)(Lds + (slot) * 32768 + \
          (wr * 128 + (mh) * 64 + m * 16 + l16) * 64 + ((lx ^ (kk << 2)) << 3)); } }
#define DSB(slot, nh) { _Pragma("unroll") for (int n = 0; n < 2; ++n) { \
    _Pragma("unroll") for (int kk = 0; kk < 2; ++kk) \
      bR[(nh) * 2 + n][kk] = *(const short8*)(Lds + (slot) * 32768 + 16384 + \
          (wc * 64 + ((nh) * 2 + n) * 16 + l16) * 64 + ((lx ^ (kk << 2)) << 3)); } }
#define QUAD(mh, nlo) { _Pragma("unroll") for (int m = 0; m < 4; ++m) \
    _Pragma("unroll") for (int n = 0; n < 2; ++n) \
    _Pragma("unroll") for (int kk = 0; kk < 2; ++kk) \
      acc[(mh) * 4 + m][(nlo) + n] = __builtin_amdgcn_mfma_f32_16x16x32_bf16( \
          aR[m][kk], bR[(nlo) + n][kk], acc[(mh) * 4 + m][(nlo) + n], 0, 0, 0); }
#define PHASE(DS, ST, MH, NLO, VM) { \
    DS; ST; \
    asm volatile("" ::: "memory"); \
    __builtin_amdgcn_s_barrier(); \
    asm volatile("s_waitcnt lgkmcnt(0)" ::: "memory"); \
    __builtin_amdgcn_sched_barrier(0); \
    __builtin_amdgcn_s_setprio(1); \
    QUAD(MH, NLO); \
    __builtin_amdgcn_s_setprio(0); \
    VM; \
    asm volatile("" ::: "memory"); \
    __builtin_amdgcn_s_barrier(); }

    for (int it = 0; it < niter; ++it) {
        int t1 = 2 * it + 1;
        int t2 = (2 * it + 2) & km;
        int t3 = (2 * it + 3) & km;
        PHASE({ DSA(0, 0); DSB(0, 0); }, { STG_A(1, 1, t1); STG_A(1, 3, t1); }, 0, 0, );
        PHASE({ DSB(0, 1); },            { STG_A(0, 0, t2); STG_A(0, 2, t2); }, 0, 2, );
        PHASE({ DSA(0, 1); },            { STG_B(0, 0, t2); STG_B(0, 1, t2); }, 1, 2, );
        PHASE({ },                       { STG_B(0, 2, t2); STG_B(0, 3, t2); }, 1, 0, vm6(); );
        PHASE({ DSA(1, 0); DSB(1, 0); }, { STG_A(0, 1, t2); STG_A(0, 3, t2); }, 0, 0, );
        PHASE({ DSB(1, 1); },            { STG_A(1, 0, t3); STG_A(1, 2, t3); }, 0, 2, );
        PHASE({ DSA(1, 1); },            { STG_B(1, 0, t3); STG_B(1, 1, t3); }, 1, 2, );
        PHASE({ },                       { STG_B(1, 2, t3); STG_B(1, 3, t3); }, 1, 0, vm6(); );
    }

    // all staged epilogues reuse LDS: drain in-flight global_load_lds first
    drainbar();
    ushort_t* Cs = Lds;

    if (MODE == 6 && bn >= 2560) {
        // V region: transposed output vbufT[d][token]; stage Cs[col][row] (row chunk-swizzled)
#pragma unroll
        for (int mi = 0; mi < 8; ++mi)
#pragma unroll
            for (int ni = 0; ni < 4; ++ni)
#pragma unroll
                for (int r = 0; r < 4; ++r) {
                    int row = wr * 128 + mi * 16 + l4 * 4 + r;
                    int col = wc * 64 + ni * 16 + l16;
                    int pch = (row >> 3) ^ (col & 7);
                    Cs[col * 256 + pch * 8 + (row & 7)] = f2b(acc[mi][ni][r]);
                }
        lbar();
        {
            int ch = tid & 31;   // token-chunk: lane-major -> coalesced along tokens
            int c0 = tid >> 5;   // 0..15
            ushort_t* Vb = (ushort_t*)C3v;
#pragma unroll
            for (int cg = 0; cg < 16; ++cg) {
                int col = cg * 16 + c0;
                int pch = ch ^ (col & 7);
                uint4 cv4 = *(const uint4*)(Cs + col * 256 + pch * 8);
                *(uint4*)(Vb + (size_t)(bn - 2560 + col) * 4096 + bm + ch * 8) = cv4;
            }
        }
    } else {
        // row-major staged epilogue (MODE 0/2/3 and MODE 6 Q/K regions)
#pragma unroll
        for (int mi = 0; mi < 8; ++mi)
#pragma unroll
            for (int ni = 0; ni < 4; ++ni)
#pragma unroll
                for (int r = 0; r < 4; ++r) {
                    int row = wr * 128 + mi * 16 + l4 * 4 + r;
                    int col = wc * 64 + ni * 16 + l16;
                    int pch = (col >> 3) ^ (row & 7);
                    Cs[row * 256 + pch * 8 + (col & 7)] = f2b(acc[mi][ni][r]);
                }
        lbar();
        {
            int ch = tid & 31;   // chunk within row: lane-major -> coalesced
            int r0 = tid >> 5;   // 0..15
            ushort_t* dst;
            int ostride, ocoff;
            if (MODE == 6) {
                if (bn < 2048) { dst = (ushort_t*)Cv;  ostride = 2048; ocoff = bn; }
                else           { dst = (ushort_t*)C2v; ostride = 512;  ocoff = bn - 2048; }
            } else {
                dst = (ushort_t*)Cv; ostride = N; ocoff = bn;
            }
#pragma unroll
            for (int rg = 0; rg < 16; ++rg) {
                int row = rg * 16 + r0;
                int pch = ch ^ (row & 7);
                uint4 cv4 = *(const uint4*)(Cs + row * 256 + pch * 8);
                size_t g = (size_t)(bm + row) * ostride + ocoff + ch * 8;
                if (MODE == 3) g += (size_t)blockIdx.y * M * N;
                if (MODE == 2) {
                    uint4 av4 = *(const uint4*)(aux + g);
                    const ushort_t* ce = (const ushort_t*)&cv4;
                    const ushort_t* ae = (const ushort_t*)&av4;
                    ushort_t o[8];
#pragma unroll
                    for (int j = 0; j < 8; ++j) {
                        float hh = b2f(ae[j]);
                        o[j] = f2b((hh / (1.f + __expf(-hh))) * b2f(ce[j]));
                    }
                    *(uint4*)(dst + g) = *(const uint4*)o;
                } else {
                    *(uint4*)(dst + g) = cv4;
                }
            }
        }
    }
#undef STG_A
#undef STG_B
#undef DSA
#undef DSB
#undef QUAD
#undef PHASE
}

// ---------------- 128x256 8-phase GEMM (BK=64, 8 waves, 96KB LDS) ----------------
// MODE 1: bf16 C = AB + aux (staged epilogue). MODE 5: fp32 C = AB + aux2 (scalar).
template <int MODE>
__global__ __launch_bounds__(512, 1) void gemm8h(const ushort_t* __restrict__ A,
                                                 const ushort_t* __restrict__ Bt,
                                                 const ushort_t* __restrict__ aux,
                                                 const float* __restrict__ aux2,
                                                 void* __restrict__ Cv,
                                                 int M, int N, int K) {
    __shared__ __align__(16) ushort_t Lds[2 * 24576];
    const int tid = threadIdx.x;
    const int wv = tid >> 6, lane = tid & 63;
    const int l16 = lane & 15, l4 = lane >> 4;
    const int wr = wv >> 2, wc = wv & 3;
    int nwg = gridDim.x;
    int per = nwg >> 3;
    int wg = (blockIdx.x & 7) * per + (blockIdx.x >> 3);
    int mtiles = M >> 7;
    int bx = wg & (mtiles - 1);
    int by = wg / mtiles;
    int bm = bx << 7, bn = by << 8;

    const int sr = tid >> 3;
    const int scol = (((tid & 7) ^ (sr & 7)) << 3);
    const ushort_t* gA = A + (size_t)(bm + sr) * K + scol;
    const ushort_t* gB = Bt + (size_t)(bn + sr) * K + scol;
    ushort_t* ldsw = Lds + wv * 512;

    const int ktiles = K >> 6;
    const int niter = ktiles >> 1;
    const int km = ktiles - 1;

#define HSTG_A(slot, j, kt) gload16(gA + (size_t)((j) * 64) * K + ((kt) << 6), ldsw + (slot) * 24576 + (j) * 4096)
#define HSTG_B(slot, j, kt) gload16(gB + (size_t)((j) * 64) * K + ((kt) << 6), ldsw + (slot) * 24576 + 8192 + (j) * 4096)

    HSTG_A(0, 0, 0); HSTG_A(0, 1, 0);
    HSTG_B(0, 0, 0); HSTG_B(0, 1, 0); HSTG_B(0, 2, 0); HSTG_B(0, 3, 0);
    HSTG_A(1, 0, 1); HSTG_A(1, 1, 1);
    HSTG_B(1, 0, 1); HSTG_B(1, 1, 1);
    vm4();
    asm volatile("" ::: "memory");
    __builtin_amdgcn_s_barrier();

    const int lx = l4 ^ (l16 & 7);
    floatx4 acc[4][4] = {};
    short8 aR[2][2], bR[4][2];

#define HDSA(slot, mh) { _Pragma("unroll") for (int m = 0; m < 2; ++m) { \
    _Pragma("unroll") for (int kk = 0; kk < 2; ++kk) \
      aR[m][kk] = *(const short8*)(Lds + (slot) * 24576 + \
          (wr * 64 + (mh) * 32 + m * 16 + l16) * 64 + ((lx ^ (kk << 2)) << 3)); } }
#define HDSB(slot, nh) { _Pragma("unroll") for (int n = 0; n < 2; ++n) { \
    _Pragma("unroll") for (int kk = 0; kk < 2; ++kk) \
      bR[(nh) * 2 + n][kk] = *(const short8*)(Lds + (slot) * 24576 + 8192 + \
          (wc * 64 + ((nh) * 2 + n) * 16 + l16) * 64 + ((lx ^ (kk << 2)) << 3)); } }
#define HQUAD(mh, nlo) { _Pragma("unroll") for (int m = 0; m < 2; ++m) \
    _Pragma("unroll") for (int n = 0; n < 2; ++n) \
    _Pragma("unroll") for (int kk = 0; kk < 2; ++kk) \
      acc[(mh) * 2 + m][(nlo) + n] = __builtin_amdgcn_mfma_f32_16x16x32_bf16( \
          aR[m][kk], bR[(nlo) + n][kk], acc[(mh) * 2 + m][(nlo) + n], 0, 0, 0); }
#define HPHASE(DS, ST, MH, NLO, VM) { \
    DS; ST; \
    asm volatile("" ::: "memory"); \
    __builtin_amdgcn_s_barrier(); \
    asm volatile("s_waitcnt lgkmcnt(0)" ::: "memory"); \
    __builtin_amdgcn_sched_barrier(0); \
    __builtin_amdgcn_s_setprio(1); \
    HQUAD(MH, NLO); \
    __builtin_amdgcn_s_setprio(0); \
    VM; \
    asm volatile("" ::: "memory"); \
    __builtin_amdgcn_s_barrier(); }

    for (int it = 0; it < niter; ++it) {
        int t1 = 2 * it + 1;
        int t2 = (2 * it + 2) & km;
        int t3 = (2 * it + 3) & km;
        HPHASE({ HDSA(0, 0); HDSB(0, 0); }, { HSTG_B(1, 2, t1); HSTG_B(1, 3, t1); }, 0, 0, );
        HPHASE({ HDSB(0, 1); },             { },                                     0, 2, );
        HPHASE({ HDSA(0, 1); },             { HSTG_B(0, 0, t2); HSTG_B(0, 1, t2); }, 1, 2, );
        HPHASE({ },                         { HSTG_B(0, 2, t2); HSTG_B(0, 3, t2); }, 1, 0, vm4(); );
        HPHASE({ HDSA(1, 0); HDSB(1, 0); }, { HSTG_A(0, 0, t2); HSTG_A(0, 1, t2); }, 0, 0, );
        HPHASE({ HDSB(1, 1); },             { },                                     0, 2, );
        HPHASE({ HDSA(1, 1); },             { HSTG_B(1, 0, t3); HSTG_B(1, 1, t3); }, 1, 2, );
        HPHASE({ },                         { HSTG_A(1, 0, t3); HSTG_A(1, 1, t3); }, 1, 0, vm4(); );
    }

    if (MODE == 1) {
        drainbar();
        ushort_t* Cs = Lds;
#pragma unroll
        for (int mi = 0; mi < 4; ++mi)
#pragma unroll
            for (int ni = 0; ni < 4; ++ni)
#pragma unroll
                for (int r = 0; r < 4; ++r) {
                    int row = wr * 64 + mi * 16 + l4 * 4 + r;
                    int col = wc * 64 + ni * 16 + l16;
                    int pch = (col >> 3) ^ (row & 7);
                    Cs[row * 256 + pch * 8 + (col & 7)] = f2b(acc[mi][ni][r]);
                }
        lbar();
        {
            int ch = tid & 31;
            int r0 = tid >> 5;   // 0..15
            ushort_t* Cb = (ushort_t*)Cv;
#pragma unroll
            for (int rg = 0; rg < 8; ++rg) {
                int row = rg * 16 + r0;
                int pch = ch ^ (row & 7);
                uint4 cv4 = *(const uint4*)(Cs + row * 256 + pch * 8);
                size_t g = (size_t)(bm + row) * N + bn + ch * 8;
                uint4 av4 = *(const uint4*)(aux + g);
                const ushort_t* ce = (const ushort_t*)&cv4;
                const ushort_t* ae = (const ushort_t*)&av4;
                ushort_t o[8];
#pragma unroll
                for (int j = 0; j < 8; ++j) o[j] = f2b(b2f(ce[j]) + b2f(ae[j]));
                *(uint4*)(Cb + g) = *(const uint4*)o;
            }
        }
    } else {
#pragma unroll
        for (int mi = 0; mi < 4; ++mi)
#pragma unroll
            for (int ni = 0; ni < 4; ++ni)
#pragma unroll
                for (int r = 0; r < 4; ++r) {
                    int row = bm + wr * 64 + mi * 16 + l4 * 4 + r;
                    int col = bn + wc * 64 + ni * 16 + l16;
                    size_t idx = (size_t)row * N + col;
                    ((float*)Cv)[idx] = acc[mi][ni][r] + aux2[idx];
                }
    }
#undef HSTG_A
#undef HSTG_B
#undef HDSA
#undef HDSB
#undef HQUAD
#undef HPHASE
}

// ---------------- Flash attention: QB=256, 8 waves, split-K halves, uniform 18 steps/block ----------------
#define QB 256
#define SB 64

__global__ __launch_bounds__(512, 1) void attn_kernel(const ushort_t* __restrict__ Q,
                                                      const ushort_t* __restrict__ Kb,
                                                      const ushort_t* __restrict__ VbT,
                                                      ushort_t* __restrict__ Pb,
                                                      float* __restrict__ Mb,
                                                      float* __restrict__ Lb, int Tlen) {
    const int D = 2048, KVD = 512, dh = 128;
    const int MTOK = 4096;
    const int PSZ = 32 * 2048 * 128;
    int p = blockIdx.x, h = blockIdx.y, b = blockIdx.z;
    int jsp = (p >= 4) ? 1 : 0;
    int kv = h >> 2;
    int t = threadIdx.x, wave = t >> 6, lane = t & 63;
    int l16 = lane & 15, l4 = lane >> 4;
    __shared__ __align__(16) ushort_t LdsAll[45056];
    const float scale = 0.08838834764831845f;
    const ushort_t* Kg = Kb + ((size_t)(b * Tlen) + (t >> 4)) * KVD + kv * dh + (t & 15) * 8;
    const ushort_t* Vg = VbT + (size_t)(kv * dh + (t >> 3)) * MTOK + b * Tlen + (t & 7) * 8;
    const int kw_off = (t >> 4) * 136 + (t & 15) * 8;
    const int vw_off = 17408 + (t >> 3) * 72 + (t & 7) * 8;
    unsigned int* PsB = (unsigned int*)(LdsAll + 26624);

    for (int side = 0; side < 2; ++side) {
        int qt = side ? p : (7 - p);
        if (qt >= 8) qt -= 8;
        int qbase = qt * QB;
        int qw = qbase + wave * 32;
        short8 qf[2][4];
#pragma unroll
        for (int f = 0; f < 2; ++f) {
            const ushort_t* Qrow = Q + ((size_t)(b * Tlen) + qw + f * 16 + l16) * D + h * dh;
#pragma unroll
            for (int kk = 0; kk < 4; ++kk) qf[f][kk] = *(const short8*)(Qrow + kk * 32 + l4 * 8);
        }
        floatx4 o_acc[2][8] = {};
        float m_s[2], l_s[2];
#pragma unroll
        for (int f = 0; f < 2; ++f) { m_s[f] = -1e30f; l_s[f] = 0.f; }
        int half = 2 * qt + 2;
        int st0 = jsp * half;
        int stEnd = st0 + half;
        uint4 kreg[2], vreg[2];
#pragma unroll
        for (int p4 = 0; p4 < 2; ++p4) {
            kreg[p4] = *(const uint4*)(Kg + (size_t)((size_t)st0 * SB + p4 * 32) * KVD);
            vreg[p4] = *(const uint4*)(Vg + (size_t)(p4 * 64) * MTOK + (size_t)st0 * SB);
        }
        lbar();
#pragma unroll
        for (int p4 = 0; p4 < 2; ++p4)
            *(uint4*)(LdsAll + (st0 & 1) * 8704 + kw_off + p4 * 32 * 136) = kreg[p4];
        {
            size_t off = (size_t)(st0 + 1) * SB;
#pragma unroll
            for (int p4 = 0; p4 < 2; ++p4)
                kreg[p4] = *(const uint4*)(Kg + (off + p4 * 32) * KVD);
        }
        for (int st = st0; st < stEnd; ++st) {
            int cur = st & 1;
            int s0 = st * SB;
            lbar();
#pragma unroll
            for (int p4 = 0; p4 < 2; ++p4)
                *(uint4*)(LdsAll + vw_off + p4 * 64 * 72) = vreg[p4];
            if (st + 1 < stEnd) {
#pragma unroll
                for (int p4 = 0; p4 < 2; ++p4)
                    *(uint4*)(LdsAll + (cur ^ 1) * 8704 + kw_off + p4 * 32 * 136) = kreg[p4];
            }
            if (st + 1 < stEnd) {
                size_t off = (size_t)(st + 1) * SB;
#pragma unroll
                for (int p4 = 0; p4 < 2; ++p4)
                    vreg[p4] = *(const uint4*)(Vg + (size_t)(p4 * 64) * MTOK + off);
            }
            if (st + 2 < stEnd) {
                size_t off = (size_t)(st + 2) * SB;
#pragma unroll
                for (int p4 = 0; p4 < 2; ++p4)
                    kreg[p4] = *(const uint4*)(Kg + (off + p4 * 32) * KVD);
            }
            floatx4 sa[2][4] = {};
            __builtin_amdgcn_s_setprio(1);
#pragma unroll
            for (int ss = 0; ss < 4; ++ss)
#pragma unroll
                for (int kk = 0; kk < 4; ++kk) {
                    short8 kf = *(const short8*)(LdsAll + cur * 8704 + (ss * 16 + l16) * 136 + kk * 32 + l4 * 8);
                    sa[0][ss] = __builtin_amdgcn_mfma_f32_16x16x32_bf16(kf, qf[0][kk], sa[0][ss], 0, 0, 0);
                    sa[1][ss] = __builtin_amdgcn_mfma_f32_16x16x32_bf16(kf, qf[1][kk], sa[1][ss], 0, 0, 0);
                }
            __builtin_amdgcn_s_setprio(0);
            short8 pa[2][2];
#pragma unroll
            for (int f = 0; f < 2; ++f) {
                int qcol = qw + f * 16 + l16;
                float sv[4][4];
                float pmax = -INFINITY;
#pragma unroll
                for (int ss = 0; ss < 4; ++ss)
#pragma unroll
                    for (int r = 0; r < 4; ++r) {
                        int krow = s0 + ss * 16 + l4 * 4 + r;
                        float v = sa[f][ss][r] * scale;
                        if (krow > qcol) v = -INFINITY;
                        sv[ss][r] = v;
                        pmax = fmaxf(pmax, v);
                    }
                pmax = fmaxf(pmax, __shfl_xor(pmax, 16));
                pmax = fmaxf(pmax, __shfl_xor(pmax, 32));
                bool skip = __all(pmax <= m_s[f] + 8.f);
                float mn = skip ? m_s[f] : fmaxf(m_s[f], pmax);
                float rsum = 0.f;
#pragma unroll
                for (int ss = 0; ss < 4; ++ss)
#pragma unroll
                    for (int r = 0; r < 4; ++r) {
                        float pv = __expf(sv[ss][r] - mn);
                        sv[ss][r] = pv;
                        rsum += pv;
                    }
                rsum += __shfl_xor(rsum, 16);
                rsum += __shfl_xor(rsum, 32);
                if (skip) {
                    l_s[f] += rsum;
                } else {
                    float esc = __expf(m_s[f] - mn);
                    l_s[f] = l_s[f] * esc + rsum;
                    m_s[f] = mn;
                    float ef[4];
#pragma unroll
                    for (int r = 0; r < 4; ++r) ef[r] = __shfl(esc, l4 * 4 + r);
#pragma unroll
                    for (int c = 0; c < 8; ++c)
#pragma unroll
                        for (int r = 0; r < 4; ++r) o_acc[f][c][r] *= ef[r];
                }
                unsigned int* Pw = PsB + (wave * 2 + f) * 16 * 36;
#pragma unroll
                for (int ss = 0; ss < 4; ++ss) {
                    uint2 pk;
                    pk.x = cvtpk(sv[ss][0], sv[ss][1]);
                    pk.y = cvtpk(sv[ss][2], sv[ss][3]);
                    *(uint2*)&Pw[l16 * 36 + ss * 8 + l4 * 2] = pk;
                }
#pragma unroll
                for (int kk = 0; kk < 2; ++kk) {
                    uint4 pv4 = *(const uint4*)&Pw[l16 * 36 + kk * 16 + l4 * 4];
                    pa[f][kk] = *(const short8*)&pv4;
                }
            }
            lbar();
            __builtin_amdgcn_s_setprio(1);
#pragma unroll
            for (int c = 0; c < 8; ++c)
#pragma unroll
                for (int kk = 0; kk < 2; ++kk) {
                    short8 vf = *(const short8*)(LdsAll + 17408 + (c * 16 + l16) * 72 + kk * 32 + l4 * 8);
                    o_acc[0][c] = __builtin_amdgcn_mfma_f32_16x16x32_bf16(pa[0][kk], vf, o_acc[0][c], 0, 0, 0);
                    o_acc[1][c] = __builtin_amdgcn_mfma_f32_16x16x32_bf16(pa[1][kk], vf, o_acc[1][c], 0, 0, 0);
                }
            __builtin_amdgcn_s_setprio(0);
        }
        lbar();
#pragma unroll
        for (int f = 0; f < 2; ++f) {
            if (l4 == 0) {
                int ridx = jsp * 65536 + ((b * 16 + h) << 11) + qw + f * 16 + l16;
                Mb[ridx] = m_s[f];
                Lb[ridx] = l_s[f];
            }
        }
        ushort_t* Osh = LdsAll;
#pragma unroll
        for (int f = 0; f < 2; ++f) {
            float linv[4];
#pragma unroll
            for (int r = 0; r < 4; ++r) {
                float lv = __shfl(l_s[f], l4 * 4 + r);
                linv[r] = (lv > 0.f) ? (1.f / lv) : 0.f;
            }
#pragma unroll
            for (int c = 0; c < 8; ++c)
#pragma unroll
                for (int r = 0; r < 4; ++r)
                    Osh[(wave * 32 + f * 16 + l4 * 4 + r) * 136 + c * 16 + l16] =
                        f2b(o_acc[f][c][r] * linv[r]);
        }
        lbar();
        {
            int orow = t >> 1, occ = (t & 1) * 64;
            const ushort_t* srcp = Osh + orow * 136 + occ;
            ushort_t* dstp = Pb + (size_t)jsp * PSZ +
                             ((size_t)((b * 16 + h)) * 2048 + qbase + orow) * 128 + occ;
#pragma unroll
            for (int k = 0; k < 8; ++k)
                *(uint4*)(dstp + k * 8) = *(const uint4*)(srcp + k * 8);
        }
    }
}

extern "C" void kernel_launch(void* const* d_in, const int* in_sizes, int n_in,
                              void* d_out, int out_size, void* d_ws, size_t ws_size,
                              hipStream_t stream) {
    const float* x   = (const float*)d_in[0];
    const float* n1w = (const float*)d_in[1];
    const float* n2w = (const float*)d_in[2];
    const float* Wq  = (const float*)d_in[3];
    const float* Wk  = (const float*)d_in[4];
    const float* Wv  = (const float*)d_in[5];
    const float* Wo  = (const float*)d_in[6];
    const float* Wc  = (const float*)d_in[7];
    const float* W1  = (const float*)d_in[8];
    const float* W2  = (const float*)d_in[9];
    const float* W3  = (const float*)d_in[10];
    float* out = (float*)d_out;

    const int B = 2, T = 2048, D = 2048, F = 8192, KVD = 512;
    const int M = B * T;  // 4096
    const size_t XD   = (size_t)M * D * 2;
    const size_t XDF  = (size_t)M * D * 4;
    const size_t KVSZ = (size_t)M * KVD * 2;
    const size_t MF   = (size_t)M * F * 2;
    const size_t WDD  = (size_t)D * D * 2;
    const size_t WQKV = (size_t)(D + 2 * KVD) * D * 2;
    const size_t WDF  = (size_t)D * F * 2;

    char* w = (char*)d_ws;
    ushort_t* xn    = (ushort_t*)(w);
    ushort_t* qtmp  = (ushort_t*)(w + XD);
    ushort_t* qfin  = (ushort_t*)(w + 2 * XD);
    float*    x2f   = (float*)   (w + 3 * XD);
    ushort_t* kbuf  = (ushort_t*)(w + 3 * XD + XDF);
    ushort_t* vbufT = (ushort_t*)(w + 3 * XD + XDF + KVSZ);
    ushort_t* h1    = (ushort_t*)(w + 3 * XD + XDF + 2 * KVSZ);
    char* wt = w + 3 * XD + XDF + 2 * KVSZ + MF;
    ushort_t* WqkvT = (ushort_t*)(wt);
    ushort_t* WcT   = (ushort_t*)(wt + WQKV);
    ushort_t* WoT   = (ushort_t*)(wt + WQKV + WDD);
    ushort_t* W1T   = (ushort_t*)(wt + WQKV + 2 * WDD);
    ushort_t* W3T   = (ushort_t*)(wt + WQKV + 2 * WDD + WDF);
    ushort_t* W2T   = (ushort_t*)(wt + WQKV + 2 * WDD + 2 * WDF);
    ushort_t* Pb = h1;
    float*    Mb = (float*)((char*)h1 + 2 * (size_t)32 * 2048 * 128 * 2);
    float*    Lb = Mb + 2 * 65536;

    dim3 blk(256);
    dim3 blk8(512);

    // weight transposes + fused rmsnorm1 (ids >= 15872)
    transpose_all<<<19968, blk, 0, stream>>>(
        Wq, Wk, Wv, Wc, Wo, W1, W3, W2,
        WqkvT, WqkvT + (size_t)2048 * D, WqkvT + (size_t)2560 * D,
        WcT, WoT, W1T, W3T, W2T,
        x, n1w, xn);

    gemm8<6><<<dim3((M / 256) * (3072 / 256)), blk8, 0, stream>>>(
        xn, WqkvT, nullptr, nullptr, qtmp, kbuf, vbufT, M, 3072, D, D);
    gemm8h<1><<<dim3((M / 128) * (D / 256)), blk8, 0, stream>>>(
        qtmp, WcT, qtmp, nullptr, qfin, M, D, D);
    attn_kernel<<<dim3(8, 16, B), blk8, 0, stream>>>(qfin, kbuf, vbufT, Pb, Mb, Lb, T);
    attn_merge<<<4096, blk, 0, stream>>>(Pb, Mb, Lb, qtmp);
    gemm8h<5><<<dim3((M / 128) * (D / 256)), blk8, 0, stream>>>(
        qtmp, WoT, nullptr, x, x2f, M, D, D);
    rmsnorm_kernel<<<M, blk, 0, stream>>>(x2f, n2w, xn, D);
    gemm8<0><<<dim3((M / 256) * (F / 256)), blk8, 0, stream>>>(
        xn, W1T, nullptr, nullptr, h1, nullptr, nullptr, M, F, D, D);
    gemm8<2><<<dim3((M / 256) * (F / 256)), blk8, 0, stream>>>(
        xn, W3T, h1, nullptr, h1, nullptr, nullptr, M, F, D, D);
    gemm8<3><<<dim3((M / 256) * (D / 256), 2), blk8, 0, stream>>>(
        h1, W2T, nullptr, nullptr, xn, nullptr, nullptr, M, D, F / 2, F);
    reduce_out<<<1024, blk, 0, stream>>>(xn, x2f, out, M * D);
}

// Round 27
// 708.941 us; speedup vs baseline: 1.0236x; 1.0236x over previous
//
#include <hip/hip_runtime.h>
#include <hip/hip_bf16.h>

typedef __attribute__((ext_vector_type(8))) short short8;
typedef __attribute__((ext_vector_type(4))) float floatx4;
typedef unsigned short ushort_t;

__device__ inline float b2f(ushort_t s) {
    return __uint_as_float(((unsigned int)s) << 16);
}
__device__ inline ushort_t f2b(float f) {
    unsigned int u = __float_as_uint(f);
    unsigned int r = 0x7fff + ((u >> 16) & 1);
    return (ushort_t)((u + r) >> 16);
}
__device__ inline unsigned int cvtpk(float lo, float hi) {
    unsigned int r;
    asm("v_cvt_pk_bf16_f32 %0, %1, %2" : "=v"(r) : "v"(lo), "v"(hi));
    return r;
}
__device__ inline void load8(const float* p, float* f) {
    float4 a = *(const float4*)p;
    float4 b = *(const float4*)(p + 4);
    f[0] = a.x; f[1] = a.y; f[2] = a.z; f[3] = a.w;
    f[4] = b.x; f[5] = b.y; f[6] = b.z; f[7] = b.w;
}
__device__ inline void gload16(const ushort_t* g, ushort_t* l) {
    __builtin_amdgcn_global_load_lds(
        (const __attribute__((address_space(1))) unsigned int*)g,
        (__attribute__((address_space(3))) unsigned int*)l, 16, 0, 0);
}
__device__ inline void lbar() {
    asm volatile("s_waitcnt lgkmcnt(0)" ::: "memory");
    __builtin_amdgcn_s_barrier();
    asm volatile("" ::: "memory");
}
__device__ inline void drainbar() {
    asm volatile("s_waitcnt vmcnt(0) lgkmcnt(0)" ::: "memory");
    __builtin_amdgcn_s_barrier();
    asm volatile("" ::: "memory");
}

// ---------- merged pre-pass: weight fp32 [K,N] -> bf16 [N,K]  +  rmsnorm1 (ids >= 15872) ----------
// W1 (branch 5) and W3 (branch 6) interleave into a shared WfT: 128-col blocks alternate
// rowbase = (nb>>7)*256 + (nb&127)  (+128 for W3) so each 256-row block = [W1 128 | W3 128].
__global__ __launch_bounds__(256) void transpose_all(
    const float* __restrict__ s0, const float* __restrict__ s1,
    const float* __restrict__ s2, const float* __restrict__ s3,
    const float* __restrict__ s4, const float* __restrict__ s5,
    const float* __restrict__ s6, const float* __restrict__ s7,
    ushort_t* d0, ushort_t* d1, ushort_t* d2, ushort_t* d3,
    ushort_t* d4, ushort_t* d5, ushort_t* d6, ushort_t* d7,
    const float* __restrict__ xin, const float* __restrict__ n1w,
    ushort_t* __restrict__ xnout) {
    int id = blockIdx.x;
    int t = threadIdx.x;
    if (id >= 15872) {
        int row = id - 15872;
        const float* xr = xin + (size_t)row * 2048;
        float f[8];
        load8(xr + t * 8, f);
        float ss = 0.f;
#pragma unroll
        for (int i = 0; i < 8; ++i) ss += f[i] * f[i];
#pragma unroll
        for (int m = 1; m < 64; m <<= 1) ss += __shfl_xor(ss, m);
        __shared__ float wsum[4];
        if ((t & 63) == 0) wsum[t >> 6] = ss;
        __syncthreads();
        float tot = wsum[0] + wsum[1] + wsum[2] + wsum[3];
        float r = rsqrtf(tot / 2048.f + 1e-6f);
        float wf[8];
        load8(n1w + t * 8, wf);
        ushort_t o[8];
#pragma unroll
        for (int i = 0; i < 8; ++i) o[i] = f2b(f[i] * r * wf[i]);
        *(uint4*)(xnout + (size_t)row * 2048 + t * 8) = *(const uint4*)o;
        return;
    }
    const float* src; ushort_t* dst; int K, N;
    int rbm = 0;
    if (id < 1024)       { src = s0; dst = d0; K = 2048; N = 2048; }
    else if (id < 1280)  { id -= 1024;  src = s1; dst = d1; K = 2048; N = 512; }
    else if (id < 1536)  { id -= 1280;  src = s2; dst = d2; K = 2048; N = 512; }
    else if (id < 2560)  { id -= 1536;  src = s3; dst = d3; K = 2048; N = 2048; }
    else if (id < 3584)  { id -= 2560;  src = s4; dst = d4; K = 2048; N = 2048; }
    else if (id < 7680)  { id -= 3584;  src = s5; dst = d5; K = 2048; N = 8192; rbm = 1; }
    else if (id < 11776) { id -= 7680;  src = s6; dst = d6; K = 2048; N = 8192; rbm = 2; }
    else                 { id -= 11776; src = s7; dst = d7; K = 8192; N = 2048; }
    int tn = N >> 6;
    int kb = (id / tn) * 64, nb = (id % tn) * 64;
    int rowbase = nb;
    if (rbm) rowbase = ((nb >> 7) << 8) + (nb & 127) + ((rbm == 2) ? 128 : 0);
    __shared__ ushort_t tile[64][65];
#pragma unroll
    for (int i = 0; i < 4; ++i) {
        int r = (t >> 4) + i * 16;
        int c = (t & 15) * 4;
        float4 v = *(const float4*)(src + (size_t)(kb + r) * N + nb + c);
        tile[c + 0][r] = f2b(v.x);
        tile[c + 1][r] = f2b(v.y);
        tile[c + 2][r] = f2b(v.z);
        tile[c + 3][r] = f2b(v.w);
    }
    __syncthreads();
#pragma unroll
    for (int i = 0; i < 2; ++i) {
        int s = t + i * 256;
        int n = s >> 3, kc = (s & 7) * 8;
        ushort_t o[8];
#pragma unroll
        for (int j = 0; j < 8; ++j) o[j] = tile[n][kc + j];
        *(uint4*)(dst + (size_t)(rowbase + n) * K + kb + kc) = *(const uint4*)o;
    }
}

// ---------------- RMSNorm: fp32 in -> bf16 out ----------------
__global__ __launch_bounds__(256) void rmsnorm_kernel(const float* __restrict__ x,
                                                      const float* __restrict__ w,
                                                      ushort_t* __restrict__ out, int D) {
    int row = blockIdx.x;
    int t = threadIdx.x;
    const float* xr = x + (size_t)row * D;
    float f[8];
    load8(xr + t * 8, f);
    float ss = 0.f;
#pragma unroll
    for (int i = 0; i < 8; ++i) ss += f[i] * f[i];
#pragma unroll
    for (int m = 1; m < 64; m <<= 1) ss += __shfl_xor(ss, m);
    __shared__ float wsum[4];
    if ((t & 63) == 0) wsum[t >> 6] = ss;
    __syncthreads();
    float tot = wsum[0] + wsum[1] + wsum[2] + wsum[3];
    float r = rsqrtf(tot / (float)D + 1e-6f);
    float wf[8];
    load8(w + t * 8, wf);
    ushort_t o[8];
#pragma unroll
    for (int i = 0; i < 8; ++i) o[i] = f2b(f[i] * r * wf[i]);
    *(uint4*)(out + (size_t)row * D + t * 8) = *(const uint4*)o;
}

// ---------------- final reduce: out = p0 + p1 + resid ----------------
__global__ __launch_bounds__(256) void reduce_out(const ushort_t* __restrict__ p,
                                                  const float* __restrict__ resid,
                                                  float* __restrict__ out, int n) {
    int stride = gridDim.x * 256;
    for (int i = blockIdx.x * 256 + threadIdx.x; i * 8 < n; i += stride) {
        int i8 = i * 8;
        uint4 a = *(const uint4*)(p + i8);
        uint4 b = *(const uint4*)(p + n + i8);
        const ushort_t* ae = (const ushort_t*)&a;
        const ushort_t* be = (const ushort_t*)&b;
        float rr[8];
        load8(resid + i8, rr);
        float o[8];
#pragma unroll
        for (int j = 0; j < 8; ++j) o[j] = b2f(ae[j]) + b2f(be[j]) + rr[j];
        *(float4*)(out + i8) = make_float4(o[0], o[1], o[2], o[3]);
        *(float4*)(out + i8 + 4) = make_float4(o[4], o[5], o[6], o[7]);
    }
}

// ---------------- attention split-K merge ----------------
__global__ __launch_bounds__(256) void attn_merge(const ushort_t* __restrict__ Pb,
                                                  const float* __restrict__ Mb,
                                                  const float* __restrict__ Lb,
                                                  ushort_t* __restrict__ out) {
    const int PSZ = 32 * 2048 * 128;
    int t = threadIdx.x;
    int r = blockIdx.x * 16 + (t >> 4);
    int d0 = (t & 15) * 8;
    float m1 = Mb[r], l1 = Lb[r];
    float m2 = Mb[65536 + r], l2 = Lb[65536 + r];
    float ms = fmaxf(m1, m2);
    float w1 = l1 * __expf(m1 - ms);
    float w2 = l2 * __expf(m2 - ms);
    float inv = 1.f / (w1 + w2);
    w1 *= inv; w2 *= inv;
    uint4 a = *(const uint4*)(Pb + (size_t)r * 128 + d0);
    uint4 b = *(const uint4*)(Pb + (size_t)PSZ + (size_t)r * 128 + d0);
    const ushort_t* ae = (const ushort_t*)&a;
    const ushort_t* be = (const ushort_t*)&b;
    int bh = r >> 11, qrow = r & 2047;
    int bb = bh >> 4, h = bh & 15;
    ushort_t o[8];
#pragma unroll
    for (int j = 0; j < 8; ++j) o[j] = f2b(b2f(ae[j]) * w1 + b2f(be[j]) * w2);
    *(uint4*)(out + ((size_t)(bb * 2048 + qrow) * 2048) + h * 128 + d0) = *(const uint4*)o;
}

__device__ inline void vm6() { asm volatile("s_waitcnt vmcnt(6)" ::: "memory"); }
__device__ inline void vm4() { asm volatile("s_waitcnt vmcnt(4)" ::: "memory"); }

// ---------------- 256x256 8-phase GEMM (BK=64, 8 waves, XOR-8 swizzle) ----------------
// MODE 3: K-split partial ; 6: QKV split (staged, per-region) ;
// MODE 7: fused SwiGLU — B is column-interleaved [W1 128 | W3 128] per 256-block,
//         epilogue computes silu(left)*right and writes 128 cols to h[.][bn/2 ..].
template <int MODE>
__global__ __launch_bounds__(512, 2) void gemm8(const ushort_t* __restrict__ A,
                                                const ushort_t* __restrict__ Bt,
                                                const ushort_t* __restrict__ aux,
                                                const float* __restrict__ aux2,
                                                void* __restrict__ Cv,
                                                void* __restrict__ C2v,
                                                void* __restrict__ C3v,
                                                int M, int N, int Ksub, int lda) {
    __shared__ __align__(16) ushort_t Lds[2 * 32768];
    const int tid = threadIdx.x;
    const int wv = tid >> 6, lane = tid & 63;
    const int l16 = lane & 15, l4 = lane >> 4;
    const int wr = wv >> 2, wc = wv & 3;
    int nwg = gridDim.x;
    int per = nwg >> 3;
    int wg = (blockIdx.x & 7) * per + (blockIdx.x >> 3);
    int mtiles = M >> 8;
    int bx = wg & (mtiles - 1);
    int by = wg / mtiles;
    int bm = bx << 8, bn = by << 8;
    int koff = blockIdx.y * Ksub;

    const int sr = tid >> 3;
    const int scol = (((tid & 7) ^ (sr & 7)) << 3);
    const ushort_t* gA = A + (size_t)(bm + sr) * lda + scol + koff;
    const ushort_t* gB = Bt + (size_t)(bn + sr) * lda + scol + koff;
    ushort_t* ldsw = Lds + wv * 512;

    const int ktiles = Ksub >> 6;
    const int niter = ktiles >> 1;
    const int km = ktiles - 1;

#define STG_A(slot, j, kt) gload16(gA + (size_t)((j) * 64) * lda + ((kt) << 6), ldsw + (slot) * 32768 + (j) * 4096)
#define STG_B(slot, j, kt) gload16(gB + (size_t)((j) * 64) * lda + ((kt) << 6), ldsw + (slot) * 32768 + 16384 + (j) * 4096)

    STG_A(0, 0, 0); STG_A(0, 2, 0); STG_A(0, 1, 0); STG_A(0, 3, 0);
    STG_B(0, 0, 0); STG_B(0, 1, 0); STG_B(0, 2, 0); STG_B(0, 3, 0);
    STG_A(1, 0, 1); STG_A(1, 2, 1);
    STG_B(1, 0, 1); STG_B(1, 1, 1); STG_B(1, 2, 1); STG_B(1, 3, 1);
    vm6();
    asm volatile("" ::: "memory");
    __builtin_amdgcn_s_barrier();

    const int lx = l4 ^ (l16 & 7);
    floatx4 acc[8][4] = {};
    short8 aR[4][2], bR[4][2];

#define DSA(slot, mh) { _Pragma("unroll") for (int m = 0; m < 4; ++m) { \
    _Pragma("unroll") for (int kk = 0; kk < 2; ++kk) \
      aR[m][kk] = *(const short8*)(Lds + (slot) * 32768 + \
          (wr * 128 + (mh) * 64 + m * 16 + l16) * 64 + ((lx ^ (kk << 2)) << 3)); } }
#define DSB(slot, nh) { _Pragma("unroll") for (int n = 0; n < 2; ++n) { \
    _Pragma("unroll") for (int kk = 0; kk < 2; ++kk) \
      bR[(nh) * 2 + n][kk] = *(const short8*)(Lds + (slot) * 32768 + 16384 + \
          (wc * 64 + ((nh) * 2 + n) * 16 + l16) * 64 + ((lx ^ (kk << 2)) << 3)); } }
#define QUAD(mh, nlo) { _Pragma("unroll") for (int m = 0; m < 4; ++m) \
    _Pragma("unroll") for (int n = 0; n < 2; ++n) \
    _Pragma("unroll") for (int kk = 0; kk < 2; ++kk) \
      acc[(mh) * 4 + m][(nlo) + n] = __builtin_amdgcn_mfma_f32_16x16x32_bf16( \
          aR[m][kk], bR[(nlo) + n][kk], acc[(mh) * 4 + m][(nlo) + n], 0, 0, 0); }
#define PHASE(DS, ST, MH, NLO, VM) { \
    DS; ST; \
    asm volatile("" ::: "memory"); \
    __builtin_amdgcn_s_barrier(); \
    asm volatile("s_waitcnt lgkmcnt(0)" ::: "memory"); \
    __builtin_amdgcn_sched_barrier(0); \
    __builtin_amdgcn_s_setprio(1); \
    QUAD(MH, NLO); \
    __builtin_amdgcn_s_setprio(0); \
    VM; \
    asm volatile("" ::: "memory"); \
    __builtin_amdgcn_s_barrier(); }

    for (int it = 0; it < niter; ++it) {
        int t1 = 2 * it + 1;
        int t2 = (2 * it + 2) & km;
        int t3 = (2 * it + 3) & km;
        PHASE({ DSA(0, 0); DSB(0, 0); }, { STG_A(1, 1, t1); STG_A(1, 3, t1); }, 0, 0, );
        PHASE({ DSB(0, 1); },            { STG_A(0, 0, t2); STG_A(0, 2, t2); }, 0, 2, );
        PHASE({ DSA(0, 1); },            { STG_B(0, 0, t2); STG_B(0, 1, t2); }, 1, 2, );
        PHASE({ },                       { STG_B(0, 2, t2); STG_B(0, 3, t2); }, 1, 0, vm6(); );
        PHASE({ DSA(1, 0); DSB(1, 0); }, { STG_A(0, 1, t2); STG_A(0, 3, t2); }, 0, 0, );
        PHASE({ DSB(1, 1); },            { STG_A(1, 0, t3); STG_A(1, 2, t3); }, 0, 2, );
        PHASE({ DSA(1, 1); },            { STG_B(1, 0, t3); STG_B(1, 1, t3); }, 1, 2, );
        PHASE({ },                       { STG_B(1, 2, t3); STG_B(1, 3, t3); }, 1, 0, vm6(); );
    }

    // all staged epilogues reuse LDS: drain in-flight global_load_lds first
    drainbar();
    ushort_t* Cs = Lds;

    if (MODE == 6 && bn >= 2560) {
        // V region: transposed output vbufT[d][token]
#pragma unroll
        for (int mi = 0; mi < 8; ++mi)
#pragma unroll
            for (int ni = 0; ni < 4; ++ni)
#pragma unroll
                for (int r = 0; r < 4; ++r) {
                    int row = wr * 128 + mi * 16 + l4 * 4 + r;
                    int col = wc * 64 + ni * 16 + l16;
                    int pch = (row >> 3) ^ (col & 7);
                    Cs[col * 256 + pch * 8 + (row & 7)] = f2b(acc[mi][ni][r]);
                }
        lbar();
        {
            int ch = tid & 31;
            int c0 = tid >> 5;
            ushort_t* Vb = (ushort_t*)C3v;
#pragma unroll
            for (int cg = 0; cg < 16; ++cg) {
                int col = cg * 16 + c0;
                int pch = ch ^ (col & 7);
                uint4 cv4 = *(const uint4*)(Cs + col * 256 + pch * 8);
                *(uint4*)(Vb + (size_t)(bn - 2560 + col) * 4096 + bm + ch * 8) = cv4;
            }
        }
    } else if (MODE == 7) {
        // fused SwiGLU epilogue: stage row-major, then h = silu(left)*right (128 cols out)
#pragma unroll
        for (int mi = 0; mi < 8; ++mi)
#pragma unroll
            for (int ni = 0; ni < 4; ++ni)
#pragma unroll
                for (int r = 0; r < 4; ++r) {
                    int row = wr * 128 + mi * 16 + l4 * 4 + r;
                    int col = wc * 64 + ni * 16 + l16;
                    int pch = (col >> 3) ^ (row & 7);
                    Cs[row * 256 + pch * 8 + (col & 7)] = f2b(acc[mi][ni][r]);
                }
        lbar();
        {
            int ch = tid & 15;   // chunk within 128-wide output
            int r0 = tid >> 4;   // 0..31
            ushort_t* Hb = (ushort_t*)Cv;
#pragma unroll
            for (int rg = 0; rg < 8; ++rg) {
                int row = rg * 32 + r0;
                int pl = ch ^ (row & 7);
                int pr = (ch + 16) ^ (row & 7);
                uint4 lv = *(const uint4*)(Cs + row * 256 + pl * 8);
                uint4 rv = *(const uint4*)(Cs + row * 256 + pr * 8);
                const ushort_t* le = (const ushort_t*)&lv;
                const ushort_t* re = (const ushort_t*)&rv;
                ushort_t o[8];
#pragma unroll
                for (int j = 0; j < 8; ++j) {
                    float a = b2f(le[j]);
                    o[j] = f2b((a / (1.f + __expf(-a))) * b2f(re[j]));
                }
                *(uint4*)(Hb + (size_t)(bm + row) * 8192 + (bn >> 1) + ch * 8) = *(const uint4*)o;
            }
        }
    } else {
        // row-major staged epilogue (MODE 3 and MODE 6 Q/K regions)
#pragma unroll
        for (int mi = 0; mi < 8; ++mi)
#pragma unroll
            for (int ni = 0; ni < 4; ++ni)
#pragma unroll
                for (int r = 0; r < 4; ++r) {
                    int row = wr * 128 + mi * 16 + l4 * 4 + r;
                    int col = wc * 64 + ni * 16 + l16;
                    int pch = (col >> 3) ^ (row & 7);
                    Cs[row * 256 + pch * 8 + (col & 7)] = f2b(acc[mi][ni][r]);
                }
        lbar();
        {
            int ch = tid & 31;
            int r0 = tid >> 5;
            ushort_t* dst;
            int ostride, ocoff;
            if (MODE == 6) {
                if (bn < 2048) { dst = (ushort_t*)Cv;  ostride = 2048; ocoff = bn; }
                else           { dst = (ushort_t*)C2v; ostride = 512;  ocoff = bn - 2048; }
            } else {
                dst = (ushort_t*)Cv; ostride = N; ocoff = bn;
            }
#pragma unroll
            for (int rg = 0; rg < 16; ++rg) {
                int row = rg * 16 + r0;
                int pch = ch ^ (row & 7);
                uint4 cv4 = *(const uint4*)(Cs + row * 256 + pch * 8);
                size_t g = (size_t)(bm + row) * ostride + ocoff + ch * 8;
                if (MODE == 3) g += (size_t)blockIdx.y * M * N;
                *(uint4*)(dst + g) = cv4;
            }
        }
    }
#undef STG_A
#undef STG_B
#undef DSA
#undef DSB
#undef QUAD
#undef PHASE
}

// ---------------- 128x256 8-phase GEMM (BK=64, 8 waves, 96KB LDS) ----------------
// MODE 1: bf16 C = AB + aux (staged epilogue). MODE 5: fp32 C = AB + aux2 (scalar).
template <int MODE>
__global__ __launch_bounds__(512, 1) void gemm8h(const ushort_t* __restrict__ A,
                                                 const ushort_t* __restrict__ Bt,
                                                 const ushort_t* __restrict__ aux,
                                                 const float* __restrict__ aux2,
                                                 void* __restrict__ Cv,
                                                 int M, int N, int K) {
    __shared__ __align__(16) ushort_t Lds[2 * 24576];
    const int tid = threadIdx.x;
    const int wv = tid >> 6, lane = tid & 63;
    const int l16 = lane & 15, l4 = lane >> 4;
    const int wr = wv >> 2, wc = wv & 3;
    int nwg = gridDim.x;
    int per = nwg >> 3;
    int wg = (blockIdx.x & 7) * per + (blockIdx.x >> 3);
    int mtiles = M >> 7;
    int bx = wg & (mtiles - 1);
    int by = wg / mtiles;
    int bm = bx << 7, bn = by << 8;

    const int sr = tid >> 3;
    const int scol = (((tid & 7) ^ (sr & 7)) << 3);
    const ushort_t* gA = A + (size_t)(bm + sr) * K + scol;
    const ushort_t* gB = Bt + (size_t)(bn + sr) * K + scol;
    ushort_t* ldsw = Lds + wv * 512;

    const int ktiles = K >> 6;
    const int niter = ktiles >> 1;
    const int km = ktiles - 1;

#define HSTG_A(slot, j, kt) gload16(gA + (size_t)((j) * 64) * K + ((kt) << 6), ldsw + (slot) * 24576 + (j) * 4096)
#define HSTG_B(slot, j, kt) gload16(gB + (size_t)((j) * 64) * K + ((kt) << 6), ldsw + (slot) * 24576 + 8192 + (j) * 4096)

    HSTG_A(0, 0, 0); HSTG_A(0, 1, 0);
    HSTG_B(0, 0, 0); HSTG_B(0, 1, 0); HSTG_B(0, 2, 0); HSTG_B(0, 3, 0);
    HSTG_A(1, 0, 1); HSTG_A(1, 1, 1);
    HSTG_B(1, 0, 1); HSTG_B(1, 1, 1);
    vm4();
    asm volatile("" ::: "memory");
    __builtin_amdgcn_s_barrier();

    const int lx = l4 ^ (l16 & 7);
    floatx4 acc[4][4] = {};
    short8 aR[2][2], bR[4][2];

#define HDSA(slot, mh) { _Pragma("unroll") for (int m = 0; m < 2; ++m) { \
    _Pragma("unroll") for (int kk = 0; kk < 2; ++kk) \
      aR[m][kk] = *(const short8*)(Lds + (slot) * 24576 + \
          (wr * 64 + (mh) * 32 + m * 16 + l16) * 64 + ((lx ^ (kk << 2)) << 3)); } }
#define HDSB(slot, nh) { _Pragma("unroll") for (int n = 0; n < 2; ++n) { \
    _Pragma("unroll") for (int kk = 0; kk < 2; ++kk) \
      bR[(nh) * 2 + n][kk] = *(const short8*)(Lds + (slot) * 24576 + 8192 + \
          (wc * 64 + ((nh) * 2 + n) * 16 + l16) * 64 + ((lx ^ (kk << 2)) << 3)); } }
#define HQUAD(mh, nlo) { _Pragma("unroll") for (int m = 0; m < 2; ++m) \
    _Pragma("unroll") for (int n = 0; n < 2; ++n) \
    _Pragma("unroll") for (int kk = 0; kk < 2; ++kk) \
      acc[(mh) * 2 + m][(nlo) + n] = __builtin_amdgcn_mfma_f32_16x16x32_bf16( \
          aR[m][kk], bR[(nlo) + n][kk], acc[(mh) * 2 + m][(nlo) + n], 0, 0, 0); }
#define HPHASE(DS, ST, MH, NLO, VM) { \
    DS; ST; \
    asm volatile("" ::: "memory"); \
    __builtin_amdgcn_s_barrier(); \
    asm volatile("s_waitcnt lgkmcnt(0)" ::: "memory"); \
    __builtin_amdgcn_sched_barrier(0); \
    __builtin_amdgcn_s_setprio(1); \
    HQUAD(MH, NLO); \
    __builtin_amdgcn_s_setprio(0); \
    VM; \
    asm volatile("" ::: "memory"); \
    __builtin_amdgcn_s_barrier(); }

    for (int it = 0; it < niter; ++it) {
        int t1 = 2 * it + 1;
        int t2 = (2 * it + 2) & km;
        int t3 = (2 * it + 3) & km;
        HPHASE({ HDSA(0, 0); HDSB(0, 0); }, { HSTG_B(1, 2, t1); HSTG_B(1, 3, t1); }, 0, 0, );
        HPHASE({ HDSB(0, 1); },             { },                                     0, 2, );
        HPHASE({ HDSA(0, 1); },             { HSTG_B(0, 0, t2); HSTG_B(0, 1, t2); }, 1, 2, );
        HPHASE({ },                         { HSTG_B(0, 2, t2); HSTG_B(0, 3, t2); }, 1, 0, vm4(); );
        HPHASE({ HDSA(1, 0); HDSB(1, 0); }, { HSTG_A(0, 0, t2); HSTG_A(0, 1, t2); }, 0, 0, );
        HPHASE({ HDSB(1, 1); },             { },                                     0, 2, );
        HPHASE({ HDSA(1, 1); },             { HSTG_B(1, 0, t3); HSTG_B(1, 1, t3); }, 1, 2, );
        HPHASE({ },                         { HSTG_A(1, 0, t3); HSTG_A(1, 1, t3); }, 1, 0, vm4(); );
    }

    if (MODE == 1) {
        drainbar();
        ushort_t* Cs = Lds;
#pragma unroll
        for (int mi = 0; mi < 4; ++mi)
#pragma unroll
            for (int ni = 0; ni < 4; ++ni)
#pragma unroll
                for (int r = 0; r < 4; ++r) {
                    int row = wr * 64 + mi * 16 + l4 * 4 + r;
                    int col = wc * 64 + ni * 16 + l16;
                    int pch = (col >> 3) ^ (row & 7);
                    Cs[row * 256 + pch * 8 + (col & 7)] = f2b(acc[mi][ni][r]);
                }
        lbar();
        {
            int ch = tid & 31;
            int r0 = tid >> 5;
            ushort_t* Cb = (ushort_t*)Cv;
#pragma unroll
            for (int rg = 0; rg < 8; ++rg) {
                int row = rg * 16 + r0;
                int pch = ch ^ (row & 7);
                uint4 cv4 = *(const uint4*)(Cs + row * 256 + pch * 8);
                size_t g = (size_t)(bm + row) * N + bn + ch * 8;
                uint4 av4 = *(const uint4*)(aux + g);
                const ushort_t* ce = (const ushort_t*)&cv4;
                const ushort_t* ae = (const ushort_t*)&av4;
                ushort_t o[8];
#pragma unroll
                for (int j = 0; j < 8; ++j) o[j] = f2b(b2f(ce[j]) + b2f(ae[j]));
                *(uint4*)(Cb + g) = *(const uint4*)o;
            }
        }
    } else {
#pragma unroll
        for (int mi = 0; mi < 4; ++mi)
#pragma unroll
            for (int ni = 0; ni < 4; ++ni)
#pragma unroll
                for (int r = 0; r < 4; ++r) {
                    int row = bm + wr * 64 + mi * 16 + l4 * 4 + r;
                    int col = bn + wc * 64 + ni * 16 + l16;
                    size_t idx = (size_t)row * N + col;
                    ((float*)Cv)[idx] = acc[mi][ni][r] + aux2[idx];
                }
    }
#undef HSTG_A
#undef HSTG_B
#undef HDSA
#undef HDSB
#undef HQUAD
#undef HPHASE
}

// ---------------- Flash attention: QB=256, 8 waves, split-K halves, uniform 18 steps/block ----------------
#define QB 256
#define SB 64

__global__ __launch_bounds__(512, 1) void attn_kernel(const ushort_t* __restrict__ Q,
                                                      const ushort_t* __restrict__ Kb,
                                                      const ushort_t* __restrict__ VbT,
                                                      ushort_t* __restrict__ Pb,
                                                      float* __restrict__ Mb,
                                                      float* __restrict__ Lb, int Tlen) {
    const int D = 2048, KVD = 512, dh = 128;
    const int MTOK = 4096;
    const int PSZ = 32 * 2048 * 128;
    int p = blockIdx.x, h = blockIdx.y, b = blockIdx.z;
    int jsp = (p >= 4) ? 1 : 0;
    int kv = h >> 2;
    int t = threadIdx.x, wave = t >> 6, lane = t & 63;
    int l16 = lane & 15, l4 = lane >> 4;
    __shared__ __align__(16) ushort_t LdsAll[45056];
    const float scale = 0.08838834764831845f;
    const ushort_t* Kg = Kb + ((size_t)(b * Tlen) + (t >> 4)) * KVD + kv * dh + (t & 15) * 8;
    const ushort_t* Vg = VbT + (size_t)(kv * dh + (t >> 3)) * MTOK + b * Tlen + (t & 7) * 8;
    const int kw_off = (t >> 4) * 136 + (t & 15) * 8;
    const int vw_off = 17408 + (t >> 3) * 72 + (t & 7) * 8;
    unsigned int* PsB = (unsigned int*)(LdsAll + 26624);

    for (int side = 0; side < 2; ++side) {
        int qt = side ? p : (7 - p);
        if (qt >= 8) qt -= 8;
        int qbase = qt * QB;
        int qw = qbase + wave * 32;
        short8 qf[2][4];
#pragma unroll
        for (int f = 0; f < 2; ++f) {
            const ushort_t* Qrow = Q + ((size_t)(b * Tlen) + qw + f * 16 + l16) * D + h * dh;
#pragma unroll
            for (int kk = 0; kk < 4; ++kk) qf[f][kk] = *(const short8*)(Qrow + kk * 32 + l4 * 8);
        }
        floatx4 o_acc[2][8] = {};
        float m_s[2], l_s[2];
#pragma unroll
        for (int f = 0; f < 2; ++f) { m_s[f] = -1e30f; l_s[f] = 0.f; }
        int half = 2 * qt + 2;
        int st0 = jsp * half;
        int stEnd = st0 + half;
        uint4 kreg[2], vreg[2];
#pragma unroll
        for (int p4 = 0; p4 < 2; ++p4) {
            kreg[p4] = *(const uint4*)(Kg + (size_t)((size_t)st0 * SB + p4 * 32) * KVD);
            vreg[p4] = *(const uint4*)(Vg + (size_t)(p4 * 64) * MTOK + (size_t)st0 * SB);
        }
        lbar();
#pragma unroll
        for (int p4 = 0; p4 < 2; ++p4)
            *(uint4*)(LdsAll + (st0 & 1) * 8704 + kw_off + p4 * 32 * 136) = kreg[p4];
        {
            size_t off = (size_t)(st0 + 1) * SB;
#pragma unroll
            for (int p4 = 0; p4 < 2; ++p4)
                kreg[p4] = *(const uint4*)(Kg + (off + p4 * 32) * KVD);
        }
        for (int st = st0; st < stEnd; ++st) {
            int cur = st & 1;
            int s0 = st * SB;
            lbar();
#pragma unroll
            for (int p4 = 0; p4 < 2; ++p4)
                *(uint4*)(LdsAll + vw_off + p4 * 64 * 72) = vreg[p4];
            if (st + 1 < stEnd) {
#pragma unroll
                for (int p4 = 0; p4 < 2; ++p4)
                    *(uint4*)(LdsAll + (cur ^ 1) * 8704 + kw_off + p4 * 32 * 136) = kreg[p4];
            }
            if (st + 1 < stEnd) {
                size_t off = (size_t)(st + 1) * SB;
#pragma unroll
                for (int p4 = 0; p4 < 2; ++p4)
                    vreg[p4] = *(const uint4*)(Vg + (size_t)(p4 * 64) * MTOK + off);
            }
            if (st + 2 < stEnd) {
                size_t off = (size_t)(st + 2) * SB;
#pragma unroll
                for (int p4 = 0; p4 < 2; ++p4)
                    kreg[p4] = *(const uint4*)(Kg + (off + p4 * 32) * KVD);
            }
            floatx4 sa[2][4] = {};
            __builtin_amdgcn_s_setprio(1);
#pragma unroll
            for (int ss = 0; ss < 4; ++ss)
#pragma unroll
                for (int kk = 0; kk < 4; ++kk) {
                    short8 kf = *(const short8*)(LdsAll + cur * 8704 + (ss * 16 + l16) * 136 + kk * 32 + l4 * 8);
                    sa[0][ss] = __builtin_amdgcn_mfma_f32_16x16x32_bf16(kf, qf[0][kk], sa[0][ss], 0, 0, 0);
                    sa[1][ss] = __builtin_amdgcn_mfma_f32_16x16x32_bf16(kf, qf[1][kk], sa[1][ss], 0, 0, 0);
                }
            __builtin_amdgcn_s_setprio(0);
            short8 pa[2][2];
#pragma unroll
            for (int f = 0; f < 2; ++f) {
                int qcol = qw + f * 16 + l16;
                float sv[4][4];
                float pmax = -INFINITY;
#pragma unroll
                for (int ss = 0; ss < 4; ++ss)
#pragma unroll
                    for (int r = 0; r < 4; ++r) {
                        int krow = s0 + ss * 16 + l4 * 4 + r;
                        float v = sa[f][ss][r] * scale;
                        if (krow > qcol) v = -INFINITY;
                        sv[ss][r] = v;
                        pmax = fmaxf(pmax, v);
                    }
                pmax = fmaxf(pmax, __shfl_xor(pmax, 16));
                pmax = fmaxf(pmax, __shfl_xor(pmax, 32));
                bool skip = __all(pmax <= m_s[f] + 8.f);
                float mn = skip ? m_s[f] : fmaxf(m_s[f], pmax);
                float rsum = 0.f;
#pragma unroll
                for (int ss = 0; ss < 4; ++ss)
#pragma unroll
                    for (int r = 0; r < 4; ++r) {
                        float pv = __expf(sv[ss][r] - mn);
                        sv[ss][r] = pv;
                        rsum += pv;
                    }
                rsum += __shfl_xor(rsum, 16);
                rsum += __shfl_xor(rsum, 32);
                if (skip) {
                    l_s[f] += rsum;
                } else {
                    float esc = __expf(m_s[f] - mn);
                    l_s[f] = l_s[f] * esc + rsum;
                    m_s[f] = mn;
                    float ef[4];
#pragma unroll
                    for (int r = 0; r < 4; ++r) ef[r] = __shfl(esc, l4 * 4 + r);
#pragma unroll
                    for (int c = 0; c < 8; ++c)
#pragma unroll
                        for (int r = 0; r < 4; ++r) o_acc[f][c][r] *= ef[r];
                }
                unsigned int* Pw = PsB + (wave * 2 + f) * 16 * 36;
#pragma unroll
                for (int ss = 0; ss < 4; ++ss) {
                    uint2 pk;
                    pk.x = cvtpk(sv[ss][0], sv[ss][1]);
                    pk.y = cvtpk(sv[ss][2], sv[ss][3]);
                    *(uint2*)&Pw[l16 * 36 + ss * 8 + l4 * 2] = pk;
                }
#pragma unroll
                for (int kk = 0; kk < 2; ++kk) {
                    uint4 pv4 = *(const uint4*)&Pw[l16 * 36 + kk * 16 + l4 * 4];
                    pa[f][kk] = *(const short8*)&pv4;
                }
            }
            lbar();
            __builtin_amdgcn_s_setprio(1);
#pragma unroll
            for (int c = 0; c < 8; ++c)
#pragma unroll
                for (int kk = 0; kk < 2; ++kk) {
                    short8 vf = *(const short8*)(LdsAll + 17408 + (c * 16 + l16) * 72 + kk * 32 + l4 * 8);
                    o_acc[0][c] = __builtin_amdgcn_mfma_f32_16x16x32_bf16(pa[0][kk], vf, o_acc[0][c], 0, 0, 0);
                    o_acc[1][c] = __builtin_amdgcn_mfma_f32_16x16x32_bf16(pa[1][kk], vf, o_acc[1][c], 0, 0, 0);
                }
            __builtin_amdgcn_s_setprio(0);
        }
        lbar();
#pragma unroll
        for (int f = 0; f < 2; ++f) {
            if (l4 == 0) {
                int ridx = jsp * 65536 + ((b * 16 + h) << 11) + qw + f * 16 + l16;
                Mb[ridx] = m_s[f];
                Lb[ridx] = l_s[f];
            }
        }
        ushort_t* Osh = LdsAll;
#pragma unroll
        for (int f = 0; f < 2; ++f) {
            float linv[4];
#pragma unroll
            for (int r = 0; r < 4; ++r) {
                float lv = __shfl(l_s[f], l4 * 4 + r);
                linv[r] = (lv > 0.f) ? (1.f / lv) : 0.f;
            }
#pragma unroll
            for (int c = 0; c < 8; ++c)
#pragma unroll
                for (int r = 0; r < 4; ++r)
                    Osh[(wave * 32 + f * 16 + l4 * 4 + r) * 136 + c * 16 + l16] =
                        f2b(o_acc[f][c][r] * linv[r]);
        }
        lbar();
        {
            int orow = t >> 1, occ = (t & 1) * 64;
            const ushort_t* srcp = Osh + orow * 136 + occ;
            ushort_t* dstp = Pb + (size_t)jsp * PSZ +
                             ((size_t)((b * 16 + h)) * 2048 + qbase + orow) * 128 + occ;
#pragma unroll
            for (int k = 0; k < 8; ++k)
                *(uint4*)(dstp + k * 8) = *(const uint4*)(srcp + k * 8);
        }
    }
}

extern "C" void kernel_launch(void* const* d_in, const int* in_sizes, int n_in,
                              void* d_out, int out_size, void* d_ws, size_t ws_size,
                              hipStream_t stream) {
    const float* x   = (const float*)d_in[0];
    const float* n1w = (const float*)d_in[1];
    const float* n2w = (const float*)d_in[2];
    const float* Wq  = (const float*)d_in[3];
    const float* Wk  = (const float*)d_in[4];
    const float* Wv  = (const float*)d_in[5];
    const float* Wo  = (const float*)d_in[6];
    const float* Wc  = (const float*)d_in[7];
    const float* W1  = (const float*)d_in[8];
    const float* W2  = (const float*)d_in[9];
    const float* W3  = (const float*)d_in[10];
    float* out = (float*)d_out;

    const int B = 2, T = 2048, D = 2048, F = 8192, KVD = 512;
    const int M = B * T;  // 4096
    const size_t XD   = (size_t)M * D * 2;
    const size_t XDF  = (size_t)M * D * 4;
    const size_t KVSZ = (size_t)M * KVD * 2;
    const size_t MF   = (size_t)M * F * 2;
    const size_t WDD  = (size_t)D * D * 2;
    const size_t WQKV = (size_t)(D + 2 * KVD) * D * 2;
    const size_t WDF  = (size_t)D * F * 2;

    char* w = (char*)d_ws;
    ushort_t* xn    = (ushort_t*)(w);
    ushort_t* qtmp  = (ushort_t*)(w + XD);
    ushort_t* qfin  = (ushort_t*)(w + 2 * XD);
    float*    x2f   = (float*)   (w + 3 * XD);
    ushort_t* kbuf  = (ushort_t*)(w + 3 * XD + XDF);
    ushort_t* vbufT = (ushort_t*)(w + 3 * XD + XDF + KVSZ);
    ushort_t* h1    = (ushort_t*)(w + 3 * XD + XDF + 2 * KVSZ);
    char* wt = w + 3 * XD + XDF + 2 * KVSZ + MF;
    ushort_t* WqkvT = (ushort_t*)(wt);
    ushort_t* WcT   = (ushort_t*)(wt + WQKV);
    ushort_t* WoT   = (ushort_t*)(wt + WQKV + WDD);
    ushort_t* WfT   = (ushort_t*)(wt + WQKV + 2 * WDD);           // interleaved [W1|W3], 16384 x 2048
    ushort_t* W2T   = (ushort_t*)(wt + WQKV + 2 * WDD + 2 * WDF);
    ushort_t* Pb = h1;
    float*    Mb = (float*)((char*)h1 + 2 * (size_t)32 * 2048 * 128 * 2);
    float*    Lb = Mb + 2 * 65536;

    dim3 blk(256);
    dim3 blk8(512);

    // weight transposes (W1/W3 interleaved into WfT) + fused rmsnorm1 (ids >= 15872)
    transpose_all<<<19968, blk, 0, stream>>>(
        Wq, Wk, Wv, Wc, Wo, W1, W3, W2,
        WqkvT, WqkvT + (size_t)2048 * D, WqkvT + (size_t)2560 * D,
        WcT, WoT, WfT, WfT, W2T,
        x, n1w, xn);

    gemm8<6><<<dim3((M / 256) * (3072 / 256)), blk8, 0, stream>>>(
        xn, WqkvT, nullptr, nullptr, qtmp, kbuf, vbufT, M, 3072, D, D);
    gemm8h<1><<<dim3((M / 128) * (D / 256)), blk8, 0, stream>>>(
        qtmp, WcT, qtmp, nullptr, qfin, M, D, D);
    attn_kernel<<<dim3(8, 16, B), blk8, 0, stream>>>(qfin, kbuf, vbufT, Pb, Mb, Lb, T);
    attn_merge<<<4096, blk, 0, stream>>>(Pb, Mb, Lb, qtmp);
    gemm8h<5><<<dim3((M / 128) * (D / 256)), blk8, 0, stream>>>(
        qtmp, WoT, nullptr, x, x2f, M, D, D);
    rmsnorm_kernel<<<M, blk, 0, stream>>>(x2f, n2w, xn, D);
    // fused SwiGLU: one GEMM over interleaved [W1|W3], writes h = silu(xn@W1)*(xn@W3)
    gemm8<7><<<dim3((M / 256) * (16384 / 256)), blk8, 0, stream>>>(
        xn, WfT, nullptr, nullptr, h1, nullptr, nullptr, M, 16384, D, D);
    gemm8<3><<<dim3((M / 256) * (D / 256), 2), blk8, 0, stream>>>(
        h1, W2T, nullptr, nullptr, xn, nullptr, nullptr, M, D, F / 2, F);
    reduce_out<<<1024, blk, 0, stream>>>(xn, x2f, out, M * D);
}